// Round 5
// baseline (359.388 us; speedup 1.0000x reference)
//
#include <hip/hip_runtime.h>
#include <hip/hip_bf16.h>
#include <cstdint>

#define FEAT    128
#define NRBF    20
#define NATOMS  8192
#define NEDGES  262144
#define NGRAPH  128
#define APG     64
#define PI_F    3.14159265358979323846f
#define CUTOFF_F 5.0f

typedef unsigned int uint_t;
typedef unsigned short ushort_t;
typedef __attribute__((ext_vector_type(4))) float f32x4;
typedef __attribute__((ext_vector_type(4))) short short4v;
typedef __attribute__((ext_vector_type(8))) short short8;

__device__ __forceinline__ float bflo(uint_t u) { return __uint_as_float(u << 16); }
__device__ __forceinline__ float bfhi(uint_t u) { return __uint_as_float(u & 0xffff0000u); }
__device__ __forceinline__ float bfus(ushort_t u) { return __uint_as_float((uint_t)u << 16); }
__device__ __forceinline__ ushort_t f2bf(float f) {
  uint_t u = __float_as_uint(f);
  return (ushort_t)((u + 0x7fffu + ((u >> 16) & 1u)) >> 16);
}
__device__ __forceinline__ float pick4(float a0, float a1, float a2, float a3, int g) {
  return (g == 0) ? a0 : (g == 1) ? a1 : (g == 2) ? a2 : a3;
}

// ---------------------------------------------------------------- prep
// One kernel: v_j repack -> (vab u32: c0|c1, vc: c2) bf16; W1/W2/Wd -> frag-order
// swizzled bf16; Wr+br -> 21-row (k=20 is br) frag-order swizzled bf16.
__device__ __forceinline__ ushort_t swz_elem(const float* __restrict__ W, int N,
                                             int NT, int i) {
  int jj = i & 7, lane = (i >> 3) & 63, tile = i >> 9;
  int ks = tile / NT, ctg = tile - ks * NT;
  int g = lane >> 4, q = lane & 15;
  int k = 32 * ks + 4 * g + (jj & 3) + 16 * (jj >> 2);
  int c = 16 * ctg + q;
  return f2bf(W[(size_t)k * N + c]);
}

__global__ void prep_kernel(const float* __restrict__ v_j, const float* __restrict__ W1,
                            const float* __restrict__ W2, const float* __restrict__ Wd,
                            const float* __restrict__ Wr, const float* __restrict__ br,
                            uint_t* __restrict__ vab, ushort_t* __restrict__ vc,
                            ushort_t* __restrict__ w1s, ushort_t* __restrict__ w2s,
                            ushort_t* __restrict__ wds, ushort_t* __restrict__ wrs) {
  int i = blockIdx.x * 256 + threadIdx.x;
  if (i < NATOMS * FEAT) {                       // v repack
    const float* vp = v_j + (size_t)i * 3;       // i = j*128+f -> v_j[j][f][c]
    vab[i] = ((uint_t)f2bf(vp[1]) << 16) | (uint_t)f2bf(vp[0]);
    vc[i] = f2bf(vp[2]);
    return;
  }
  i -= NATOMS * FEAT;
  if (i < 16384) { w1s[i] = swz_elem(W1, 128, 8, i); return; }
  i -= 16384;
  if (i < 49152) { w2s[i] = swz_elem(W2, 384, 24, i); return; }
  i -= 49152;
  if (i < 49152) { wds[i] = swz_elem(Wd, 384, 24, i); return; }
  i -= 49152;
  if (i < 12288) {                               // Wr/br: 24 tiles, single K-step
    int jj = i & 7, lane = (i >> 3) & 63, ct = i >> 9;
    int g = lane >> 4, q = lane & 15;
    int k = 4 * g + (jj & 3) + 16 * (jj >> 2);
    int f = 16 * ct + q;
    float v = (k < NRBF) ? Wr[k * 384 + f] : (k == NRBF ? br[f] : 0.f);
    wrs[i] = f2bf(v);
  }
}

// ---------------------------------------------------------------- MFMA GEMM
// C[8192 x N] = act(A[8192 x 128] @ W + b). Tile 64x64, 4 waves, 16 MFMA/wave.
// Fragment maps verified (round-3/4 pass). omode: 1 = bf16 row out (p0),
// 2 = phi-split (p0 = pab u16-pairs, p1 = pc), 3 = qkv-split (p0 = Qf f32, p1 = kv bf16)
__global__ __launch_bounds__(256) void gemm_mfma(
    const void* __restrict__ Asrc, int a_f32, const ushort_t* __restrict__ Wswz,
    const float* __restrict__ bias, int N, int NT, int silu, int omode,
    void* __restrict__ p0, void* __restrict__ p1) {
  __shared__ ushort_t As[64][136];
  const int t = threadIdx.x;
  const int r0 = blockIdx.x * 64, c0 = blockIdx.y * 64;
  const int w = t >> 6, l = t & 63, g = l >> 4, q = l & 15;

  short8 bf[4][4];
  #pragma unroll
  for (int ks = 0; ks < 4; ++ks)
    #pragma unroll
    for (int ct = 0; ct < 4; ++ct)
      bf[ks][ct] = *reinterpret_cast<const short8*>(
          Wswz + ((size_t)(ks * NT + (c0 >> 4) + ct) * 64 + l) * 8);

  if (a_f32) {
    const float* Af = (const float*)Asrc;
    for (int i = t; i < 64 * 32; i += 256) {
      int r = i >> 5, k4 = i & 31;
      float4 v = *reinterpret_cast<const float4*>(Af + (size_t)(r0 + r) * 128 + 4 * k4);
      ushort4 o = {f2bf(v.x), f2bf(v.y), f2bf(v.z), f2bf(v.w)};
      *reinterpret_cast<ushort4*>(&As[r][4 * k4]) = o;
    }
  } else {
    const ushort_t* Ab = (const ushort_t*)Asrc;
    for (int i = t; i < 64 * 16; i += 256) {
      int r = i >> 4, g8 = i & 15;
      short8 v = *reinterpret_cast<const short8*>(Ab + (size_t)(r0 + r) * 128 + 8 * g8);
      *reinterpret_cast<short8*>(&As[r][8 * g8]) = v;
    }
  }
  __syncthreads();

  f32x4 acc[4] = {};
  #pragma unroll
  for (int ks = 0; ks < 4; ++ks) {
    const ushort_t* ap = &As[16 * w + q][32 * ks + 4 * g];
    short4v alo = *reinterpret_cast<const short4v*>(ap);
    short4v ahi = *reinterpret_cast<const short4v*>(ap + 16);
    short8 af;
    af[0] = alo[0]; af[1] = alo[1]; af[2] = alo[2]; af[3] = alo[3];
    af[4] = ahi[0]; af[5] = ahi[1]; af[6] = ahi[2]; af[7] = ahi[3];
    #pragma unroll
    for (int ct = 0; ct < 4; ++ct)
      acc[ct] = __builtin_amdgcn_mfma_f32_16x16x32_bf16(af, bf[ks][ct], acc[ct], 0, 0, 0);
  }

  #pragma unroll
  for (int ct = 0; ct < 4; ++ct) {
    int col = c0 + 16 * ct + q;
    float bb = bias[col];
    #pragma unroll
    for (int r = 0; r < 4; ++r) {
      float o = acc[ct][r] + bb;
      if (silu) o = o / (1.f + __expf(-o));
      int row = r0 + 16 * w + 4 * g + r;
      if (omode == 1) {
        ((ushort_t*)p0)[(size_t)row * N + col] = f2bf(o);
      } else if (omode == 2) {
        int f = col & 127, s = col >> 7;
        if (s < 2) ((ushort_t*)p0)[((size_t)row * 128 + f) * 2 + s] = f2bf(o);
        else       ((ushort_t*)p1)[(size_t)row * 128 + f] = f2bf(o);
      } else {
        if (col < 128) ((float*)p0)[(size_t)row * 128 + col] = o;
        else           ((ushort_t*)p1)[(size_t)row * 256 + col - 128] = f2bf(o);
      }
    }
  }
}

// ---------------------------------------------------------------- sort helpers
__global__ void zero_kernel(int* __restrict__ p, int n) {
  int i = blockIdx.x * blockDim.x + threadIdx.x;
  if (i < n) p[i] = 0;
}

__global__ void hist_kernel(const int* __restrict__ nbrs, int* __restrict__ counts) {
  int e = blockIdx.x * blockDim.x + threadIdx.x;
  if (e < NEDGES) atomicAdd(&counts[nbrs[2 * e]], 1);
}

__global__ __launch_bounds__(1024) void scan_kernel(
    const int* __restrict__ counts, int* __restrict__ offs, int* __restrict__ cursor) {
  __shared__ int part[1024];
  const int t = threadIdx.x;
  int local[8];
  int s = 0;
  #pragma unroll
  for (int i = 0; i < 8; ++i) { local[i] = counts[t * 8 + i]; s += local[i]; }
  part[t] = s;
  __syncthreads();
  for (int off = 1; off < 1024; off <<= 1) {
    int v = part[t];
    int add = (t >= off) ? part[t - off] : 0;
    __syncthreads();
    part[t] = v + add;
    __syncthreads();
  }
  int excl = part[t] - s;
  #pragma unroll
  for (int i = 0; i < 8; ++i) {
    offs[t * 8 + i] = excl;
    cursor[t * 8 + i] = excl;
    excl += local[i];
  }
  if (t == 1023) offs[NATOMS] = excl;
}

__global__ void scatter_kernel(const int* __restrict__ nbrs, int* __restrict__ cursor,
                               int* __restrict__ sorted) {
  int e = blockIdx.x * blockDim.x + threadIdx.x;
  if (e < NEDGES) {
    int seg = nbrs[2 * e];
    int pos = atomicAdd(&cursor[seg], 1);
    sorted[pos] = e;
  }
}

// ---------------------------------------------------------------- edge MFMA v2
// One wave per atom, zero LDS. Per 16-edge tile: A[16 x 32pad] = basis coeffs
// (k<20: env*sin((k+1)ang)/d, k=20: env — br folded as basis row), B = pre-swizzled
// Wr/br frags from GLOBAL (24 KB, L1-resident). Per 16-col tile ct: 3 MFMAs (one per
// section), fused epilogue with packed phi (s0|s1, s2) and v (c0|c1, c2) gathers.
// C map (HW-verified r3): row = 4g+reg = edge, col = q. Cross-g reduce at atom end.
__global__ __launch_bounds__(256) void edge_mfma2(
    const int* __restrict__ sorted, const int* __restrict__ offs,
    const int* __restrict__ nbrs, const float* __restrict__ r_ij,
    const uint_t* __restrict__ pab, const ushort_t* __restrict__ pc,
    const uint_t* __restrict__ vab, const ushort_t* __restrict__ vc,
    const ushort_t* __restrict__ wrs,
    float* __restrict__ out_s, float* __restrict__ out_v) {
  const int t = threadIdx.x, w = t >> 6, l = t & 63, g = l >> 4, q = l & 15;
  const int atom = blockIdx.x * 4 + w;
  const int start = offs[atom], end = offs[atom + 1];
  const float c1 = PI_F / CUTOFF_F;

  float ds[8] = {};
  float dv[8][3] = {};

  for (int eb = start; eb < end; eb += 16) {
    // ---- metadata: lane q owns edge eb+q (replicated across g)
    float ang = 0.f, ie = 0.f, env = 0.f, u0 = 0.f, u1 = 0.f, u2 = 0.f;
    int jn = 0;
    if (eb + q < end) {
      int e = sorted[eb + q];
      float x = r_ij[3 * e], y = r_ij[3 * e + 1], z = r_ij[3 * e + 2];
      jn = nbrs[2 * e + 1];
      float d = sqrtf(x * x + y * y + z * z);
      float inv = 1.f / d;
      ang = c1 * d;
      env = (d < CUTOFF_F) ? 0.5f * (__cosf(ang) + 1.f) : 0.f;
      ie = inv * env;
      u0 = x * inv; u1 = y * inv; u2 = z * inv;
    }
    // ---- A fragment: k = kmap(g,jj)
    short8 af;
    #pragma unroll
    for (int jj = 0; jj < 8; ++jj) {
      int k = 4 * g + (jj & 3) + 16 * (jj >> 2);
      float v = (k < NRBF) ? ie * __sinf((float)(k + 1) * ang)
                           : (k == NRBF ? env : 0.f);
      af[jj] = (short)f2bf(v);
    }
    // ---- row (edge eb+4g+r) metadata broadcast
    int jbase[4];
    float ub[4][3];
    #pragma unroll
    for (int r = 0; r < 4; ++r) {
      int src = 4 * g + r;
      jbase[r] = __shfl(jn, src, 64) * 128 + q;
      ub[r][0] = __shfl(u0, src, 64);
      ub[r][1] = __shfl(u1, src, 64);
      ub[r][2] = __shfl(u2, src, 64);
    }
    // ---- 8 col-tiles x 3 sections
    #pragma unroll
    for (int ct = 0; ct < 8; ++ct) {
      short8 b0 = *reinterpret_cast<const short8*>(wrs + ((ct) * 64 + l) * 8);
      short8 b1 = *reinterpret_cast<const short8*>(wrs + ((8 + ct) * 64 + l) * 8);
      short8 b2 = *reinterpret_cast<const short8*>(wrs + ((16 + ct) * 64 + l) * 8);
      f32x4 z4 = {0.f, 0.f, 0.f, 0.f};
      f32x4 cs0 = __builtin_amdgcn_mfma_f32_16x16x32_bf16(af, b0, z4, 0, 0, 0);
      f32x4 cs1 = __builtin_amdgcn_mfma_f32_16x16x32_bf16(af, b1, z4, 0, 0, 0);
      f32x4 cs2 = __builtin_amdgcn_mfma_f32_16x16x32_bf16(af, b2, z4, 0, 0, 0);
      #pragma unroll
      for (int r = 0; r < 4; ++r) {
        int fidx = jbase[r] + 16 * ct;
        uint_t pv = pab[fidx];
        uint_t vv = vab[fidx];
        float p2 = bfus(pc[fidx]);
        float vz = bfus(vc[fidx]);
        float pw0 = bflo(pv) * cs0[r];
        ds[ct] += bfhi(pv) * cs1[r];
        float pw2 = p2 * cs2[r];
        dv[ct][0] += pw0 * bflo(vv) + pw2 * ub[r][0];
        dv[ct][1] += pw0 * bfhi(vv) + pw2 * ub[r][1];
        dv[ct][2] += pw0 * vz + pw2 * ub[r][2];
      }
    }
  }

  // ---- reduce the 4 g-copies (each accumulated different edge rows)
  #pragma unroll
  for (int ct = 0; ct < 8; ++ct) {
    float x = ds[ct];
    x += __shfl_xor(x, 16, 64); x += __shfl_xor(x, 32, 64);
    ds[ct] = x;
    #pragma unroll
    for (int c = 0; c < 3; ++c) {
      float y = dv[ct][c];
      y += __shfl_xor(y, 16, 64); y += __shfl_xor(y, 32, 64);
      dv[ct][c] = y;
    }
  }
  // ---- write: lane (g,q) owns ct = 2g, 2g+1 (compile-time picks, no scratch)
  #pragma unroll
  for (int i2 = 0; i2 < 2; ++i2) {
    float sv = i2 ? pick4(ds[1], ds[3], ds[5], ds[7], g)
                  : pick4(ds[0], ds[2], ds[4], ds[6], g);
    float d0 = i2 ? pick4(dv[1][0], dv[3][0], dv[5][0], dv[7][0], g)
                  : pick4(dv[0][0], dv[2][0], dv[4][0], dv[6][0], g);
    float d1 = i2 ? pick4(dv[1][1], dv[3][1], dv[5][1], dv[7][1], g)
                  : pick4(dv[0][1], dv[2][1], dv[4][1], dv[6][1], g);
    float d2 = i2 ? pick4(dv[1][2], dv[3][2], dv[5][2], dv[7][2], g)
                  : pick4(dv[0][2], dv[2][2], dv[4][2], dv[6][2], g);
    int f = 16 * (2 * g + i2) + q;
    out_s[(size_t)atom * FEAT + f] = sv;
    float* ov = out_v + (size_t)atom * 384 + (size_t)f * 3;
    ov[0] = d0; ov[1] = d1; ov[2] = d2;
  }
}

// ---------------------------------------------------------------- attention
__device__ __forceinline__ float wave_max64(float v) {
  #pragma unroll
  for (int m = 32; m > 0; m >>= 1) v = fmaxf(v, __shfl_xor(v, m, 64));
  return v;
}
__device__ __forceinline__ float wave_sum64(float v) {
  #pragma unroll
  for (int m = 32; m > 0; m >>= 1) v += __shfl_xor(v, m, 64);
  return v;
}

__global__ __launch_bounds__(256) void attn_kernel(const float* __restrict__ Qf,
                                                   const ushort_t* __restrict__ kvbf,
                                                   float* __restrict__ out_s) {
  __shared__ float4 Ks4[64 * 32];
  __shared__ float  Vs[64][130];
  __shared__ float  Ps[4][4][64];
  const int b = blockIdx.x >> 1, half = blockIdx.x & 1;
  const int t = threadIdx.x;
  const float* qbase = Qf + (size_t)b * APG * 128;
  const ushort_t* kvb = kvbf + (size_t)b * APG * 256;

  for (int i = t; i < 64 * 32; i += 256) {
    int a = i >> 5, gg = i & 31;
    ushort4 k4 = *reinterpret_cast<const ushort4*>(kvb + a * 256 + 4 * gg);
    float4 kf = {bfus(k4.x), bfus(k4.y), bfus(k4.z), bfus(k4.w)};
    Ks4[a * 32 + (gg ^ (a & 7))] = kf;
  }
  for (int i = t; i < 64 * 32; i += 256) {
    int a = i >> 5, gg = i & 31;
    ushort4 v4 = *reinterpret_cast<const ushort4*>(kvb + a * 256 + 128 + 4 * gg);
    Vs[a][4 * gg + 0] = bfus(v4.x); Vs[a][4 * gg + 1] = bfus(v4.y);
    Vs[a][4 * gg + 2] = bfus(v4.z); Vs[a][4 * gg + 3] = bfus(v4.w);
  }
  __syncthreads();

  const int w = t >> 6, l = t & 63;
  const float scale = 0.08838834764831845f;

  for (int qq = 8 * half + w; qq < 8 * half + 8; qq += 4) {
    const float* q0p = qbase + (size_t)(4 * qq + 0) * 128;
    const float* q1p = qbase + (size_t)(4 * qq + 1) * 128;
    const float* q2p = qbase + (size_t)(4 * qq + 2) * 128;
    const float* q3p = qbase + (size_t)(4 * qq + 3) * 128;
    float s0 = 0.f, s1 = 0.f, s2 = 0.f, s3 = 0.f;
    #pragma unroll 8
    for (int i = 0; i < 32; ++i) {
      float4 k = Ks4[l * 32 + (i ^ (l & 7))];
      float4 q0 = *reinterpret_cast<const float4*>(q0p + 4 * i);
      float4 q1 = *reinterpret_cast<const float4*>(q1p + 4 * i);
      float4 q2 = *reinterpret_cast<const float4*>(q2p + 4 * i);
      float4 q3 = *reinterpret_cast<const float4*>(q3p + 4 * i);
      s0 += q0.x * k.x + q0.y * k.y + q0.z * k.z + q0.w * k.w;
      s1 += q1.x * k.x + q1.y * k.y + q1.z * k.z + q1.w * k.w;
      s2 += q2.x * k.x + q2.y * k.y + q2.z * k.z + q2.w * k.w;
      s3 += q3.x * k.x + q3.y * k.y + q3.z * k.z + q3.w * k.w;
    }
    s0 *= scale; s1 *= scale; s2 *= scale; s3 *= scale;

    float p0 = __expf(s0 - wave_max64(s0));
    float p1 = __expf(s1 - wave_max64(s1));
    float p2 = __expf(s2 - wave_max64(s2));
    float p3 = __expf(s3 - wave_max64(s3));
    p0 /= wave_sum64(p0); p1 /= wave_sum64(p1);
    p2 /= wave_sum64(p2); p3 /= wave_sum64(p3);

    Ps[w][0][l] = p0; Ps[w][1][l] = p1; Ps[w][2][l] = p2; Ps[w][3][l] = p3;
    __threadfence_block();

    float a00 = 0.f, a01 = 0.f, a10 = 0.f, a11 = 0.f;
    float a20 = 0.f, a21 = 0.f, a30 = 0.f, a31 = 0.f;
    for (int a = 0; a < 64; ++a) {
      float2 v = *reinterpret_cast<const float2*>(&Vs[a][2 * l]);
      float pa0 = Ps[w][0][a], pa1 = Ps[w][1][a];
      float pa2 = Ps[w][2][a], pa3 = Ps[w][3][a];
      a00 += pa0 * v.x; a01 += pa0 * v.y;
      a10 += pa1 * v.x; a11 += pa1 * v.y;
      a20 += pa2 * v.x; a21 += pa2 * v.y;
      a30 += pa3 * v.x; a31 += pa3 * v.y;
    }
    size_t row0 = (size_t)(b * APG + 4 * qq) * FEAT + 2 * l;
    float2* o0 = reinterpret_cast<float2*>(out_s + row0);
    float2* o1 = reinterpret_cast<float2*>(out_s + row0 + FEAT);
    float2* o2 = reinterpret_cast<float2*>(out_s + row0 + 2 * FEAT);
    float2* o3 = reinterpret_cast<float2*>(out_s + row0 + 3 * FEAT);
    float2 c0 = *o0; c0.x += a00; c0.y += a01; *o0 = c0;
    float2 c1 = *o1; c1.x += a10; c1.y += a11; *o1 = c1;
    float2 c2 = *o2; c2.x += a20; c2.y += a21; *o2 = c2;
    float2 c3 = *o3; c3.x += a30; c3.y += a31; *o3 = c3;
    __threadfence_block();
  }
}

// ---------------------------------------------------------------- launch
extern "C" void kernel_launch(void* const* d_in, const int* in_sizes, int n_in,
                              void* d_out, int out_size, void* d_ws, size_t ws_size,
                              hipStream_t stream) {
  const float* s_j  = (const float*)d_in[0];
  const float* v_j  = (const float*)d_in[1];
  const float* r_ij = (const float*)d_in[2];
  const int*   nbrs = (const int*)d_in[3];
  const float* W1   = (const float*)d_in[5];
  const float* b1   = (const float*)d_in[6];
  const float* W2   = (const float*)d_in[7];
  const float* b2   = (const float*)d_in[8];
  const float* Wr   = (const float*)d_in[9];
  const float* br   = (const float*)d_in[10];
  const float* Wd   = (const float*)d_in[11];
  const float* bd   = (const float*)d_in[12];

  float* out_s = (float*)d_out;
  float* out_v = out_s + (size_t)NATOMS * FEAT;

  // workspace: 23.3 MB
  float*    Qf   = (float*)d_ws;                         // 8192*128 f32
  ushort_t* kvbf = (ushort_t*)(Qf + NATOMS * FEAT);      // 8192*256 bf16
  uint_t*   pab  = (uint_t*)(kvbf + NATOMS * 256);       // 8192*128 u32 (phi s0|s1)
  ushort_t* pc   = (ushort_t*)(pab + NATOMS * FEAT);     // 8192*128 (phi s2)
  uint_t*   vab  = (uint_t*)(pc + NATOMS * FEAT);        // 8192*128 u32 (v c0|c1)
  ushort_t* vc   = (ushort_t*)(vab + NATOMS * FEAT);     // 8192*128 (v c2)
  ushort_t* w1s  = vc + NATOMS * FEAT;                   // 16384
  ushort_t* w2s  = w1s + 16384;                          // 49152
  ushort_t* wds  = w2s + 49152;                          // 49152
  ushort_t* wrs  = wds + 49152;                          // 12288
  ushort_t* h_bf = wrs + 12288;                          // 8192*128 bf16 (dead after gemm2)
  int* sorted = (int*)h_bf;                              // alias after gemm2
  int* offs   = sorted + NEDGES;
  int* cursor = offs + (NATOMS + 1);
  int* counts = cursor + NATOMS;

  int prep_total = NATOMS * FEAT + 16384 + 49152 + 49152 + 12288;
  prep_kernel<<<(prep_total + 255) / 256, 256, 0, stream>>>(
      v_j, W1, W2, Wd, Wr, br, vab, vc, w1s, w2s, wds, wrs);

  gemm_mfma<<<dim3(NATOMS / 64, 2), 256, 0, stream>>>(
      s_j, 1, w1s, b1, 128, 8, 1, 1, h_bf, nullptr);
  gemm_mfma<<<dim3(NATOMS / 64, 6), 256, 0, stream>>>(
      h_bf, 0, w2s, b2, 384, 24, 0, 2, pab, pc);

  zero_kernel<<<(NATOMS + 255) / 256, 256, 0, stream>>>(counts, NATOMS);
  hist_kernel<<<NEDGES / 256, 256, 0, stream>>>(nbrs, counts);
  scan_kernel<<<1, 1024, 0, stream>>>(counts, offs, cursor);
  scatter_kernel<<<NEDGES / 256, 256, 0, stream>>>(nbrs, cursor, sorted);

  gemm_mfma<<<dim3(NATOMS / 64, 6), 256, 0, stream>>>(
      s_j, 1, wds, bd, 384, 24, 0, 3, Qf, kvbf);

  edge_mfma2<<<NATOMS / 4, 256, 0, stream>>>(sorted, offs, nbrs, r_ij, pab, pc,
                                             vab, vc, wrs, out_s, out_v);
  attn_kernel<<<NGRAPH * 2, 256, 0, stream>>>(Qf, kvbf, out_s);
}

// Round 6
// 216.582 us; speedup vs baseline: 1.6594x; 1.6594x over previous
//
#include <hip/hip_runtime.h>
#include <hip/hip_bf16.h>
#include <cstdint>

#define FEAT    128
#define NRBF    20
#define NATOMS  8192
#define NEDGES  262144
#define NGRAPH  128
#define APG     64
#define PI_F    3.14159265358979323846f
#define CUTOFF_F 5.0f
#define ECH     6

typedef unsigned int uint_t;
typedef unsigned short ushort_t;
typedef __attribute__((ext_vector_type(2))) float f32x2;
typedef __attribute__((ext_vector_type(4))) float f32x4;
typedef __attribute__((ext_vector_type(4))) short short4v;
typedef __attribute__((ext_vector_type(8))) short short8;

#if __has_builtin(__builtin_elementwise_fma)
#define PKFMA(a, b, c) __builtin_elementwise_fma((a), (b), (c))
#else
#define PKFMA(a, b, c) ((a) * (b) + (c))
#endif

__device__ __forceinline__ float bflo(uint_t u) { return __uint_as_float(u << 16); }
__device__ __forceinline__ float bfhi(uint_t u) { return __uint_as_float(u & 0xffff0000u); }
__device__ __forceinline__ float bfus(ushort_t u) { return __uint_as_float((uint_t)u << 16); }
__device__ __forceinline__ ushort_t f2bf(float f) {
  uint_t u = __float_as_uint(f);
  return (ushort_t)((u + 0x7fffu + ((u >> 16) & 1u)) >> 16);
}

// ---------------------------------------------------------------- prep
// V-pack: Vpack[j][l] = 6 bf16 {v(2l,c0),v(2l,c1),v(2l,c2),v(2l+1,c0),v(2l+1,c1),v(2l+1,c2)}
// + frag-order swizzled bf16 weights for the three dense GEMMs.
__device__ __forceinline__ ushort_t swz_elem(const float* __restrict__ W, int N,
                                             int NT, int i) {
  int jj = i & 7, lane = (i >> 3) & 63, tile = i >> 9;
  int ks = tile / NT, ctg = tile - ks * NT;
  int g = lane >> 4, q = lane & 15;
  int k = 32 * ks + 4 * g + (jj & 3) + 16 * (jj >> 2);
  int c = 16 * ctg + q;
  return f2bf(W[(size_t)k * N + c]);
}

__global__ void prep_kernel(const float* __restrict__ v_j, const float* __restrict__ W1,
                            const float* __restrict__ W2, const float* __restrict__ Wd,
                            uint4* __restrict__ Vpack, ushort_t* __restrict__ w1s,
                            ushort_t* __restrict__ w2s, ushort_t* __restrict__ wds) {
  int i = blockIdx.x * 256 + threadIdx.x;
  if (i < NATOMS * 64) {
    const float* vp = v_j + (size_t)i * 6;   // i = j*64+l -> v_j[j][2l][0]
    float2 a = *reinterpret_cast<const float2*>(vp);
    float2 b = *reinterpret_cast<const float2*>(vp + 2);
    float2 c = *reinterpret_cast<const float2*>(vp + 4);
    uint4 u;
    u.x = ((uint_t)f2bf(a.y) << 16) | (uint_t)f2bf(a.x);
    u.y = ((uint_t)f2bf(b.y) << 16) | (uint_t)f2bf(b.x);
    u.z = ((uint_t)f2bf(c.y) << 16) | (uint_t)f2bf(c.x);
    u.w = 0u;
    Vpack[i] = u;
    return;
  }
  i -= NATOMS * 64;
  if (i < 16384) { w1s[i] = swz_elem(W1, 128, 8, i); return; }
  i -= 16384;
  if (i < 49152) { w2s[i] = swz_elem(W2, 384, 24, i); return; }
  i -= 49152;
  if (i < 49152) { wds[i] = swz_elem(Wd, 384, 24, i); return; }
}

// ---------------------------------------------------------------- MFMA GEMM
// C[8192 x N] = act(A[8192 x 128] @ W + b). Tile 64x64, 4 waves, 16 MFMA/wave.
// Fragment maps HW-verified (rounds 3-5). omode: 1 = bf16 row out (p0),
// 2 = phi Ppack (p0: [row][64] uint4, slot s*2+(f&1)), 3 = qkv-split (p0 Qf f32, p1 kv bf16)
__global__ __launch_bounds__(256) void gemm_mfma(
    const void* __restrict__ Asrc, int a_f32, const ushort_t* __restrict__ Wswz,
    const float* __restrict__ bias, int N, int NT, int silu, int omode,
    void* __restrict__ p0, void* __restrict__ p1) {
  __shared__ ushort_t As[64][136];
  const int t = threadIdx.x;
  const int r0 = blockIdx.x * 64, c0 = blockIdx.y * 64;
  const int w = t >> 6, l = t & 63, g = l >> 4, q = l & 15;

  short8 bf[4][4];
  #pragma unroll
  for (int ks = 0; ks < 4; ++ks)
    #pragma unroll
    for (int ct = 0; ct < 4; ++ct)
      bf[ks][ct] = *reinterpret_cast<const short8*>(
          Wswz + ((size_t)(ks * NT + (c0 >> 4) + ct) * 64 + l) * 8);

  if (a_f32) {
    const float* Af = (const float*)Asrc;
    for (int i = t; i < 64 * 32; i += 256) {
      int r = i >> 5, k4 = i & 31;
      float4 v = *reinterpret_cast<const float4*>(Af + (size_t)(r0 + r) * 128 + 4 * k4);
      ushort4 o = {f2bf(v.x), f2bf(v.y), f2bf(v.z), f2bf(v.w)};
      *reinterpret_cast<ushort4*>(&As[r][4 * k4]) = o;
    }
  } else {
    const ushort_t* Ab = (const ushort_t*)Asrc;
    for (int i = t; i < 64 * 16; i += 256) {
      int r = i >> 4, g8 = i & 15;
      short8 v = *reinterpret_cast<const short8*>(Ab + (size_t)(r0 + r) * 128 + 8 * g8);
      *reinterpret_cast<short8*>(&As[r][8 * g8]) = v;
    }
  }
  __syncthreads();

  f32x4 acc[4] = {};
  #pragma unroll
  for (int ks = 0; ks < 4; ++ks) {
    const ushort_t* ap = &As[16 * w + q][32 * ks + 4 * g];
    short4v alo = *reinterpret_cast<const short4v*>(ap);
    short4v ahi = *reinterpret_cast<const short4v*>(ap + 16);
    short8 af;
    af[0] = alo[0]; af[1] = alo[1]; af[2] = alo[2]; af[3] = alo[3];
    af[4] = ahi[0]; af[5] = ahi[1]; af[6] = ahi[2]; af[7] = ahi[3];
    #pragma unroll
    for (int ct = 0; ct < 4; ++ct)
      acc[ct] = __builtin_amdgcn_mfma_f32_16x16x32_bf16(af, bf[ks][ct], acc[ct], 0, 0, 0);
  }

  #pragma unroll
  for (int ct = 0; ct < 4; ++ct) {
    int col = c0 + 16 * ct + q;
    float bb = bias[col];
    #pragma unroll
    for (int r = 0; r < 4; ++r) {
      float o = acc[ct][r] + bb;
      if (silu) o = o / (1.f + __expf(-o));
      int row = r0 + 16 * w + 4 * g + r;
      if (omode == 1) {
        ((ushort_t*)p0)[(size_t)row * N + col] = f2bf(o);
      } else if (omode == 2) {
        int f = col & 127, s = col >> 7;
        ((ushort_t*)p0)[((size_t)row * 64 + (f >> 1)) * 8 + s * 2 + (f & 1)] = f2bf(o);
      } else {
        if (col < 128) ((float*)p0)[(size_t)row * 128 + col] = o;
        else           ((ushort_t*)p1)[(size_t)row * 256 + col - 128] = f2bf(o);
      }
    }
  }
}

// ---------------------------------------------------------------- sort helpers
__global__ void zero_kernel(int* __restrict__ p, int n) {
  int i = blockIdx.x * blockDim.x + threadIdx.x;
  if (i < n) p[i] = 0;
}

__global__ void hist_kernel(const int* __restrict__ nbrs, int* __restrict__ counts) {
  int e = blockIdx.x * blockDim.x + threadIdx.x;
  if (e < NEDGES) atomicAdd(&counts[nbrs[2 * e]], 1);
}

__global__ __launch_bounds__(1024) void scan_kernel(
    const int* __restrict__ counts, int* __restrict__ offs, int* __restrict__ cursor) {
  __shared__ int part[1024];
  const int t = threadIdx.x;
  int local[8];
  int s = 0;
  #pragma unroll
  for (int i = 0; i < 8; ++i) { local[i] = counts[t * 8 + i]; s += local[i]; }
  part[t] = s;
  __syncthreads();
  for (int off = 1; off < 1024; off <<= 1) {
    int v = part[t];
    int add = (t >= off) ? part[t - off] : 0;
    __syncthreads();
    part[t] = v + add;
    __syncthreads();
  }
  int excl = part[t] - s;
  #pragma unroll
  for (int i = 0; i < 8; ++i) {
    offs[t * 8 + i] = excl;
    cursor[t * 8 + i] = excl;
    excl += local[i];
  }
  if (t == 1023) offs[NATOMS] = excl;
}

__global__ void scatter_kernel(const int* __restrict__ nbrs, int* __restrict__ cursor,
                               int* __restrict__ sorted) {
  int e = blockIdx.x * blockDim.x + threadIdx.x;
  if (e < NEDGES) {
    int seg = nbrs[2 * e];
    int pos = atomicAdd(&cursor[seg], 1);
    sorted[pos] = e;
  }
}

// ---------------------------------------------------------------- edge accumulation
// Round-4 structure (one wave/atom, 6-edge chunks, LDS Wr bf16-pairs + pre-splatted
// rbf), with packed gathers: per edge per lane exactly TWO b128 loads (Ppack, Vpack)
// instead of six scattered loads.
__global__ __launch_bounds__(256) void edge_accum3(
    const int* __restrict__ sorted, const int* __restrict__ offs,
    const int* __restrict__ nbrs, const float* __restrict__ r_ij,
    const uint4* __restrict__ Pp, const uint4* __restrict__ Vp,
    const float* __restrict__ Wr, const float* __restrict__ br,
    float* __restrict__ out_s, float* __restrict__ out_v) {
  __shared__ uint_t sWrp[3 * NRBF * 64];   // bf16-pair packed, 15360 B
  __shared__ f32x2 eR2[4][ECH][NRBF];      // pre-splatted rbf, 3840 B
  __shared__ float eU[4][ECH][3];
  __shared__ float eE[4][ECH];
  __shared__ int   eJ[4][ECH];

  const int t = threadIdx.x;
  for (int i = t; i < 3 * NRBF * 64; i += 256) {
    int l2 = i & 63, sn = i >> 6;
    int s = sn / NRBF, n = sn - s * NRBF;
    float w0 = Wr[n * 384 + s * 128 + 2 * l2];
    float w1 = Wr[n * 384 + s * 128 + 2 * l2 + 1];
    sWrp[i] = ((uint_t)f2bf(w1) << 16) | (uint_t)f2bf(w0);
  }
  __syncthreads();

  const int w = t >> 6, l = t & 63;
  const int atom = blockIdx.x * 4 + w;
  const int start = offs[atom], end = offs[atom + 1];
  const float c1 = PI_F / CUTOFF_F;

  float2 br0 = *reinterpret_cast<const float2*>(br + 2 * l);
  float2 br1 = *reinterpret_cast<const float2*>(br + 128 + 2 * l);
  float2 br2 = *reinterpret_cast<const float2*>(br + 256 + 2 * l);

  float ds0 = 0.f, ds1 = 0.f;
  float dv00 = 0.f, dv01 = 0.f, dv02 = 0.f;
  float dv10 = 0.f, dv11 = 0.f, dv12 = 0.f;

  for (int base = start; base < end; base += ECH) {
    __threadfence_block();  // WAR: previous chunk reads done before overwrite
    #pragma unroll
    for (int rr = 0; rr < 2; ++rr) {
      int task = l + rr * 64;
      if (task < ECH * NRBF) {
        int el = task / NRBF;
        int n = task - el * NRBF;
        int eidx = base + el;
        float rbfv = 0.f;
        if (eidx < end) {
          int e = sorted[eidx];
          float x = r_ij[3 * e], y = r_ij[3 * e + 1], z = r_ij[3 * e + 2];
          float d = sqrtf(x * x + y * y + z * z);
          float env = 0.f;
          if (d < CUTOFF_F) env = 0.5f * (__cosf(c1 * d) + 1.f);
          float inv = 1.f / d;
          rbfv = __sinf((float)(n + 1) * c1 * d) * inv * env;
          if (n == 0) {
            eJ[w][el] = nbrs[2 * e + 1];
            eE[w][el] = env;
            eU[w][el][0] = x * inv;
            eU[w][el][1] = y * inv;
            eU[w][el][2] = z * inv;
          }
        } else if (n == 0) {
          eJ[w][el] = 0;
          eE[w][el] = 0.f;
          eU[w][el][0] = 0.f; eU[w][el][1] = 0.f; eU[w][el][2] = 0.f;
        }
        eR2[w][el][n] = (f32x2){rbfv, rbfv};
      }
    }
    __threadfence_block();  // setup writes visible before reads

    // ---- issue packed gathers up front: 2 b128 per edge per lane
    uint4 pg[ECH], vg[ECH];
    #pragma unroll
    for (int el = 0; el < ECH; ++el) {
      int jl = eJ[w][el] * 64 + l;
      pg[el] = Pp[jl];
      vg[el] = Vp[jl];
    }

    // ---- wsv: f32x2 packed, 3 sections x 6 edges per rbf term
    float envb[ECH];
    #pragma unroll
    for (int el = 0; el < ECH; ++el) envb[el] = eE[w][el];
    f32x2 wsv[ECH][3];
    #pragma unroll
    for (int el = 0; el < ECH; ++el) {
      wsv[el][0] = (f32x2){envb[el] * br0.x, envb[el] * br0.y};
      wsv[el][1] = (f32x2){envb[el] * br1.x, envb[el] * br1.y};
      wsv[el][2] = (f32x2){envb[el] * br2.x, envb[el] * br2.y};
    }
    #pragma unroll
    for (int n = 0; n < NRBF; ++n) {
      uint_t u0 = sWrp[(0 * NRBF + n) * 64 + l];
      uint_t u1 = sWrp[(1 * NRBF + n) * 64 + l];
      uint_t u2 = sWrp[(2 * NRBF + n) * 64 + l];
      f32x2 w0 = (f32x2){bflo(u0), bfhi(u0)};
      f32x2 w1 = (f32x2){bflo(u1), bfhi(u1)};
      f32x2 w2 = (f32x2){bflo(u2), bfhi(u2)};
      #pragma unroll
      for (int el = 0; el < ECH; ++el) {
        f32x2 rn2 = eR2[w][el][n];
        wsv[el][0] = PKFMA(rn2, w0, wsv[el][0]);
        wsv[el][1] = PKFMA(rn2, w1, wsv[el][1]);
        wsv[el][2] = PKFMA(rn2, w2, wsv[el][2]);
      }
    }

    // ---- epilogue: unpack packed gathers, accumulate
    #pragma unroll
    for (int el = 0; el < ECH; ++el) {
      float u0 = eU[w][el][0], u1 = eU[w][el][1], u2 = eU[w][el][2];
      float p00 = bflo(pg[el].x), p01 = bfhi(pg[el].x);
      float p10 = bflo(pg[el].y), p11 = bfhi(pg[el].y);
      float p20 = bflo(pg[el].z), p21 = bfhi(pg[el].z);
      float vax = bflo(vg[el].x), vay = bfhi(vg[el].x);
      float vbx = bflo(vg[el].y), vby = bfhi(vg[el].y);
      float vcx = bflo(vg[el].z), vcy = bfhi(vg[el].z);
      float s00 = p00 * wsv[el][0].x, s01 = p01 * wsv[el][0].y;
      ds0 += p10 * wsv[el][1].x;
      ds1 += p11 * wsv[el][1].y;
      float s20 = p20 * wsv[el][2].x, s21 = p21 * wsv[el][2].y;
      dv00 += s20 * u0 + s00 * vax;
      dv01 += s20 * u1 + s00 * vay;
      dv02 += s20 * u2 + s00 * vbx;
      dv10 += s21 * u0 + s01 * vby;
      dv11 += s21 * u1 + s01 * vcx;
      dv12 += s21 * u2 + s01 * vcy;
    }
  }

  *reinterpret_cast<float2*>(out_s + (size_t)atom * FEAT + 2 * l) = make_float2(ds0, ds1);
  float* ov = out_v + (size_t)atom * 384 + 6 * l;
  *reinterpret_cast<float2*>(ov)     = make_float2(dv00, dv01);
  *reinterpret_cast<float2*>(ov + 2) = make_float2(dv02, dv10);
  *reinterpret_cast<float2*>(ov + 4) = make_float2(dv11, dv12);
}

// ---------------------------------------------------------------- attention
__device__ __forceinline__ float wave_max64(float v) {
  #pragma unroll
  for (int m = 32; m > 0; m >>= 1) v = fmaxf(v, __shfl_xor(v, m, 64));
  return v;
}
__device__ __forceinline__ float wave_sum64(float v) {
  #pragma unroll
  for (int m = 32; m > 0; m >>= 1) v += __shfl_xor(v, m, 64);
  return v;
}

__global__ __launch_bounds__(256) void attn_kernel(const float* __restrict__ Qf,
                                                   const ushort_t* __restrict__ kvbf,
                                                   float* __restrict__ out_s) {
  __shared__ float4 Ks4[64 * 32];
  __shared__ float  Vs[64][130];
  __shared__ float  Ps[4][4][64];
  const int b = blockIdx.x >> 1, half = blockIdx.x & 1;
  const int t = threadIdx.x;
  const float* qbase = Qf + (size_t)b * APG * 128;
  const ushort_t* kvb = kvbf + (size_t)b * APG * 256;

  for (int i = t; i < 64 * 32; i += 256) {
    int a = i >> 5, gg = i & 31;
    ushort4 k4 = *reinterpret_cast<const ushort4*>(kvb + a * 256 + 4 * gg);
    float4 kf = {bfus(k4.x), bfus(k4.y), bfus(k4.z), bfus(k4.w)};
    Ks4[a * 32 + (gg ^ (a & 7))] = kf;
  }
  for (int i = t; i < 64 * 32; i += 256) {
    int a = i >> 5, gg = i & 31;
    ushort4 v4 = *reinterpret_cast<const ushort4*>(kvb + a * 256 + 128 + 4 * gg);
    Vs[a][4 * gg + 0] = bfus(v4.x); Vs[a][4 * gg + 1] = bfus(v4.y);
    Vs[a][4 * gg + 2] = bfus(v4.z); Vs[a][4 * gg + 3] = bfus(v4.w);
  }
  __syncthreads();

  const int w = t >> 6, l = t & 63;
  const float scale = 0.08838834764831845f;

  for (int qq = 8 * half + w; qq < 8 * half + 8; qq += 4) {
    const float* q0p = qbase + (size_t)(4 * qq + 0) * 128;
    const float* q1p = qbase + (size_t)(4 * qq + 1) * 128;
    const float* q2p = qbase + (size_t)(4 * qq + 2) * 128;
    const float* q3p = qbase + (size_t)(4 * qq + 3) * 128;
    float s0 = 0.f, s1 = 0.f, s2 = 0.f, s3 = 0.f;
    #pragma unroll 8
    for (int i = 0; i < 32; ++i) {
      float4 k = Ks4[l * 32 + (i ^ (l & 7))];
      float4 q0 = *reinterpret_cast<const float4*>(q0p + 4 * i);
      float4 q1 = *reinterpret_cast<const float4*>(q1p + 4 * i);
      float4 q2 = *reinterpret_cast<const float4*>(q2p + 4 * i);
      float4 q3 = *reinterpret_cast<const float4*>(q3p + 4 * i);
      s0 += q0.x * k.x + q0.y * k.y + q0.z * k.z + q0.w * k.w;
      s1 += q1.x * k.x + q1.y * k.y + q1.z * k.z + q1.w * k.w;
      s2 += q2.x * k.x + q2.y * k.y + q2.z * k.z + q2.w * k.w;
      s3 += q3.x * k.x + q3.y * k.y + q3.z * k.z + q3.w * k.w;
    }
    s0 *= scale; s1 *= scale; s2 *= scale; s3 *= scale;

    float p0 = __expf(s0 - wave_max64(s0));
    float p1 = __expf(s1 - wave_max64(s1));
    float p2 = __expf(s2 - wave_max64(s2));
    float p3 = __expf(s3 - wave_max64(s3));
    p0 /= wave_sum64(p0); p1 /= wave_sum64(p1);
    p2 /= wave_sum64(p2); p3 /= wave_sum64(p3);

    Ps[w][0][l] = p0; Ps[w][1][l] = p1; Ps[w][2][l] = p2; Ps[w][3][l] = p3;
    __threadfence_block();

    float a00 = 0.f, a01 = 0.f, a10 = 0.f, a11 = 0.f;
    float a20 = 0.f, a21 = 0.f, a30 = 0.f, a31 = 0.f;
    for (int a = 0; a < 64; ++a) {
      float2 v = *reinterpret_cast<const float2*>(&Vs[a][2 * l]);
      float pa0 = Ps[w][0][a], pa1 = Ps[w][1][a];
      float pa2 = Ps[w][2][a], pa3 = Ps[w][3][a];
      a00 += pa0 * v.x; a01 += pa0 * v.y;
      a10 += pa1 * v.x; a11 += pa1 * v.y;
      a20 += pa2 * v.x; a21 += pa2 * v.y;
      a30 += pa3 * v.x; a31 += pa3 * v.y;
    }
    size_t row0 = (size_t)(b * APG + 4 * qq) * FEAT + 2 * l;
    float2* o0 = reinterpret_cast<float2*>(out_s + row0);
    float2* o1 = reinterpret_cast<float2*>(out_s + row0 + FEAT);
    float2* o2 = reinterpret_cast<float2*>(out_s + row0 + 2 * FEAT);
    float2* o3 = reinterpret_cast<float2*>(out_s + row0 + 3 * FEAT);
    float2 c0 = *o0; c0.x += a00; c0.y += a01; *o0 = c0;
    float2 c1 = *o1; c1.x += a10; c1.y += a11; *o1 = c1;
    float2 c2 = *o2; c2.x += a20; c2.y += a21; *o2 = c2;
    float2 c3 = *o3; c3.x += a30; c3.y += a31; *o3 = c3;
    __threadfence_block();
  }
}

// ---------------------------------------------------------------- launch
extern "C" void kernel_launch(void* const* d_in, const int* in_sizes, int n_in,
                              void* d_out, int out_size, void* d_ws, size_t ws_size,
                              hipStream_t stream) {
  const float* s_j  = (const float*)d_in[0];
  const float* v_j  = (const float*)d_in[1];
  const float* r_ij = (const float*)d_in[2];
  const int*   nbrs = (const int*)d_in[3];
  const float* W1   = (const float*)d_in[5];
  const float* b1   = (const float*)d_in[6];
  const float* W2   = (const float*)d_in[7];
  const float* b2   = (const float*)d_in[8];
  const float* Wr   = (const float*)d_in[9];
  const float* br   = (const float*)d_in[10];
  const float* Wd   = (const float*)d_in[11];
  const float* bd   = (const float*)d_in[12];

  float* out_s = (float*)d_out;
  float* out_v = out_s + (size_t)NATOMS * FEAT;

  // workspace: ~26.2 MB (<= 26.4 MB proven in round 1)
  float*    Qf    = (float*)d_ws;                        // 8192*128 f32   (4 MB)
  ushort_t* kvbf  = (ushort_t*)(Qf + NATOMS * FEAT);     // 8192*256 bf16  (4 MB)
  uint4*    Ppack = (uint4*)(kvbf + NATOMS * 256);       // 8192*64 uint4  (8 MB)
  uint4*    Vpack = Ppack + (size_t)NATOMS * 64;         // 8192*64 uint4  (8 MB)
  ushort_t* w1s   = (ushort_t*)(Vpack + (size_t)NATOMS * 64);  // 16384
  ushort_t* w2s   = w1s + 16384;                         // 49152
  ushort_t* wds   = w2s + 49152;                         // 49152
  ushort_t* h_bf  = wds + 49152;                         // 8192*128 bf16 (2 MB, dead after gemm2)
  int* sorted = (int*)h_bf;                              // alias after gemm2
  int* offs   = sorted + NEDGES;
  int* cursor = offs + (NATOMS + 1);
  int* counts = cursor + NATOMS;

  int prep_total = NATOMS * 64 + 16384 + 49152 + 49152;
  prep_kernel<<<(prep_total + 255) / 256, 256, 0, stream>>>(
      v_j, W1, W2, Wd, Vpack, w1s, w2s, wds);

  gemm_mfma<<<dim3(NATOMS / 64, 2), 256, 0, stream>>>(
      s_j, 1, w1s, b1, 128, 8, 1, 1, h_bf, nullptr);
  gemm_mfma<<<dim3(NATOMS / 64, 6), 256, 0, stream>>>(
      h_bf, 0, w2s, b2, 384, 24, 0, 2, Ppack, nullptr);

  zero_kernel<<<(NATOMS + 255) / 256, 256, 0, stream>>>(counts, NATOMS);
  hist_kernel<<<NEDGES / 256, 256, 0, stream>>>(nbrs, counts);
  scan_kernel<<<1, 1024, 0, stream>>>(counts, offs, cursor);
  scatter_kernel<<<NEDGES / 256, 256, 0, stream>>>(nbrs, cursor, sorted);

  gemm_mfma<<<dim3(NATOMS / 64, 6), 256, 0, stream>>>(
      s_j, 1, wds, bd, 384, 24, 0, 3, Qf, kvbf);

  edge_accum3<<<NATOMS / 4, 256, 0, stream>>>(sorted, offs, nbrs, r_ij, Ppack,
                                              Vpack, Wr, br, out_s, out_v);
  attn_kernel<<<NGRAPH * 2, 256, 0, stream>>>(Qf, kvbf, out_s);
}